// Round 6
// baseline (2652.084 us; speedup 1.0000x reference)
//
#include <hip/hip_runtime.h>
#include <cmath>

// ConvLSTM2D forward, bf16 MFMA implicit GEMM, R11: single persistent kernel,
// all 16 timesteps fused, hand-rolled device-scope grid barrier (512 blocks,
// residency-by-construction: 67.4KB LDS, ~210 regs <= 256 -> 2 blocks/CU).
// B=8, T=16, H=W=96, Cin=8, F=64 (4F=256 gates), 3x3 SAME.
// R5-R10 lesson: every inner-loop variant lands 33-46us/step vs 12.2us MFMA
// floor with all pipes <25% busy -> the 16-dispatch structure (launch+ramp+
// drain+L2 flush+cS HBM round-trip per step) is the wall, not the loop.
// R11 structure: block = 12x12 tile x 4 slices (wave=slice), 4x4 M-units
// (9 units/wave, pure imm addressing); c in LDS across ALL steps (cS HBM
// traffic gone); h: own tile in LDS planes, border-only global store,
// 52-pos ring re-staged per step from double-buffered global h.
// Barrier: 1 release-add + acquire-spin per step (15 total), agent scope.

#define HTOT 96
#define WTOT 96
#define CINX 8
#define FF   64
#define G4   256
#define BB   8
#define TT   16
#define NPOS (BB*HTOT*WTOT)        // 73728 global positions
#define NBLK 512

typedef __attribute__((ext_vector_type(8))) short short8;   // 8 bf16 = 4 VGPRs
typedef __attribute__((ext_vector_type(4))) float floatx4;

union U16 { uint4 u; short8 s; };

__device__ __forceinline__ float hsig(float z) {
    return fminf(fmaxf(0.2f * z + 0.5f, 0.f), 1.f);
}

__device__ __forceinline__ float ftanh(float x) {
    float e = __expf(-2.f * fabsf(x));
    float t = (1.f - e) / (1.f + e);
    return copysignf(t, x);
}

__device__ __forceinline__ ushort f2bf(float f) {            // RNE fp32->bf16
    unsigned u = __float_as_uint(f);
    u = (u + 0x7fff + ((u >> 16) & 1)) >> 16;
    return (ushort)u;
}

// async 16B global->LDS; LDS dest = uniform base + lane*16 (linear in tid)
__device__ __forceinline__ void async16(const void* g, void* l) {
    __builtin_amdgcn_global_load_lds(
        (const __attribute__((address_space(1))) void*)g,
        (__attribute__((address_space(3))) void*)l, 16, 0, 0);
}

// ---- prep: x fp32 -> bf16 (all T at once), layout [b,t,y,x,8] ----
__global__ __launch_bounds__(256) void conv_x_bf16(const float* __restrict__ x,
                                                   ushort* __restrict__ xbf, int n4) {
    int i = blockIdx.x * 256 + threadIdx.x;
    if (i >= n4) return;
    float4 v = ((const float4*)x)[i];
    ushort4 o;
    o.x = f2bf(v.x); o.y = f2bf(v.y); o.z = f2bf(v.z); o.w = f2bf(v.w);
    ((ushort4*)xbf)[i] = o;
}

// ---- prep: weights -> per-slice slab stream, slab s order = dx*6 + kh*3 + dy ----
// Bp[(slice*21+s)*256 + g*64 + lane] (16B units); lane(q,col) holds B rows q*8..q*8+7
__global__ __launch_bounds__(256) void prep_w(const float* __restrict__ Wx,
                                              const float* __restrict__ Wh,
                                              ushort* __restrict__ Bp) {
    int idx = blockIdx.x * 256 + threadIdx.x;
    if (idx >= 4 * 21 * 256) return;                 // 21504
    int lane = idx & 63;
    int g = (idx >> 6) & 3;
    int rest = idx >> 8;                             // slice*21 + s
    int s = rest % 21, slice = rest / 21;
    int q = lane >> 4, col = lane & 15;
    int n = g * 64 + slice * 16 + col;
    ushort o[8];
    if (s < 18) {
        int dxw = s / 6, rem = s - 6 * dxw;
        int khw = rem / 3, dyw = rem - 3 * khw;
        int tap = dyw * 3 + dxw;
        int cbase = khw * 32 + q * 8;
        #pragma unroll
        for (int j = 0; j < 8; ++j)
            o[j] = f2bf(Wh[((size_t)tap * FF + cbase + j) * G4 + n]);
    } else {
        int tap = (s - 18) * 4 + q;                  // packed x-taps; >8 -> zero pad
        #pragma unroll
        for (int j = 0; j < 8; ++j)
            o[j] = (tap < 9) ? f2bf(Wx[((size_t)tap * CINX + j) * G4 + n]) : (ushort)0;
    }
    U16 u;
    #pragma unroll
    for (int j = 0; j < 8; ++j) ((ushort*)&u)[j] = o[j];
    ((uint4*)Bp)[idx] = u.u;
}

// ---- fused 16-step kernel ----
__global__ __launch_bounds__(256, 2) void convlstm_fused(
    const ushort* __restrict__ xbf,
    ushort* __restrict__ hG0,             // h parity buffers [slice][pos][16] bf16
    ushort* __restrict__ hG1,
    const ushort* __restrict__ Bp,
    const float* __restrict__ bias,
    const uint4* __restrict__ zpad,       // 64B zeros for OOB x staging
    unsigned* __restrict__ cnt,           // grid barrier counter (zeroed)
    float* __restrict__ out)
{
    // h halo planes: plane pl = kh*4+q holds 8 ch (kh*32+q*8..) for 14x14 pos
    __shared__ __align__(16) ushort hplanes[8 * 1568];   // 25088 B
    __shared__ __align__(16) ushort xplane[1568];        //  3136 B (14x14 x 8ch)
    __shared__ __align__(16) float  cL[9792];            // 39168 B c-state (padded)

    const int tid = threadIdx.x;
    const int x0 = blockIdx.x * 12, y0 = blockIdx.y * 12, bb = blockIdx.z;
    const int w = tid >> 6, lane = tid & 63, q = lane >> 4, col = lane & 15;
    const int sig = w;                                   // wave = slice

    const uint4* gBu = (const uint4*)Bp + (size_t)(sig * 21) * 256 + lane;

    // per-lane A offsets: M-unit u = (uy,ux) covers 4x4 pos; A-row m = col:
    // pos (y,x) = (uy*4 + (col>>2), ux*4 + (col&3)); halo idx = (y+dy)*14+(x+dx)
    int aoffu[9];
    #pragma unroll
    for (int u = 0; u < 9; ++u) {
        int uy = u / 3, ux = u % 3;
        int yu = uy * 4 + (col >> 2), xu = ux * 4 + (col & 3);
        aoffu[u] = (yu * 14 + xu) * 8;                   // ushort offset
    }
    int xdo[3];
    #pragma unroll
    for (int sx = 0; sx < 3; ++sx) {
        int tap = sx * 4 + q; if (tap > 8) tap = 8;      // padded taps: B rows 0
        xdo[sx] = ((tap / 3) * 14 + (tap % 3)) * 8;
    }
    float bv[4];
    #pragma unroll
    for (int g = 0; g < 4; ++g) bv[g] = bias[g * 64 + sig * 16 + col];

    const int ple = (sig >> 1) * 4 + (sig & 1) * 2 + (col >> 3);  // epilogue plane

    // zero-init LDS (h(-1) = 0, c(0) = 0)
    uint4 z4 = make_uint4(0, 0, 0, 0);
    for (int i = tid; i < 1568; i += 256) ((uint4*)hplanes)[i] = z4;
    for (int i = tid; i < 2448; i += 256) ((uint4*)cL)[i] = z4;

    for (int t = 0; t < TT; ++t) {
        // ---- grid barrier: all blocks finished step t-1 ----
        if (t) {
            if (tid == 0) {
                unsigned target = (unsigned)(NBLK * t);
                while (__hip_atomic_load(cnt, __ATOMIC_ACQUIRE,
                                         __HIP_MEMORY_SCOPE_AGENT) < target)
                    __builtin_amdgcn_s_sleep(2);
            }
            __syncthreads();
        }
        const ushort* hin = (t & 1) ? hG0 : hG1;         // h(t-1)
        ushort* hout      = (t & 1) ? hG1 : hG0;         // h(t)

        // ---- stage 52-pos halo ring of h(t-1) from neighbors ----
        for (int e = tid; e < 416; e += 256) {
            int r = e >> 3, pl = e & 7;
            int py, px;
            if (r < 14)      { py = 0;  px = r; }
            else if (r < 28) { py = 13; px = r - 14; }
            else { int e2 = r - 28; py = 1 + (e2 >> 1); px = (e2 & 1) ? 13 : 0; }
            int gy = y0 - 1 + py, gx = x0 - 1 + px;
            if ((unsigned)gy < (unsigned)HTOT && (unsigned)gx < (unsigned)WTOT) {
                int sl = (pl >> 2) * 2 + ((pl & 3) >> 1), hf = pl & 1;
                size_t gpos = ((size_t)bb * HTOT + gy) * WTOT + gx;
                uint4 v = *(const uint4*)(hin + ((size_t)sl * NPOS + gpos) * 16 + hf * 8);
                *(uint4*)(hplanes + pl * 1568 + (py * 14 + px) * 8) = v;
            } // OOB ring entries stay zero from init (never written)
        }
        // ---- stage x(t) 14x14 halo (async, lane-linear dest) ----
        if (tid < 196) {
            int py = tid / 14, px = tid % 14;
            int gy = y0 - 1 + py, gx = x0 - 1 + px;
            bool ok = ((unsigned)gy < (unsigned)HTOT && (unsigned)gx < (unsigned)WTOT);
            const void* src = ok
                ? (const void*)(xbf + ((((size_t)bb * TT + t) * HTOT + gy) * WTOT + gx) * CINX)
                : (const void*)zpad;
            async16(src, xplane + tid * 8);
        }

        floatx4 acc[9][4];
        #pragma unroll
        for (int g = 0; g < 4; ++g) {
            float b0 = bv[g];
            #pragma unroll
            for (int u = 0; u < 9; ++u) acc[u][g] = (floatx4){b0, b0, b0, b0};
        }

        __syncthreads();   // ring ds_writes + x async16 drained; planes ready

        // ---- K-loop: 18 h-steps (dx,kh,dy) + 3 x-steps; B dbuf in regs ----
        U16 bbuf[2][4];
        #pragma unroll
        for (int g = 0; g < 4; ++g) bbuf[0][g].u = gBu[g * 64];
        const ushort* hAq = hplanes + q * 1568;
        #pragma unroll
        for (int dx = 0; dx < 3; ++dx)
        #pragma unroll
        for (int kh = 0; kh < 2; ++kh)
        #pragma unroll
        for (int dy = 0; dy < 3; ++dy) {
            const int s = dx * 6 + kh * 3 + dy;
            if (s < 20) {
                #pragma unroll
                for (int g = 0; g < 4; ++g)
                    bbuf[(s + 1) & 1][g].u = gBu[(s + 1) * 256 + g * 64];
            }
            #pragma unroll
            for (int u = 0; u < 9; ++u) {
                U16 a;
                a.u = *(const uint4*)(hAq + kh * 6272 + aoffu[u] + (dy * 14 + dx) * 8);
                #pragma unroll
                for (int g = 0; g < 4; ++g)
                    acc[u][g] = __builtin_amdgcn_mfma_f32_16x16x32_bf16(
                        a.s, bbuf[s & 1][g].s, acc[u][g], 0, 0, 0);
            }
        }
        #pragma unroll
        for (int sx = 0; sx < 3; ++sx) {
            const int s = 18 + sx;
            if (s < 20) {
                #pragma unroll
                for (int g = 0; g < 4; ++g)
                    bbuf[(s + 1) & 1][g].u = gBu[(s + 1) * 256 + g * 64];
            }
            #pragma unroll
            for (int u = 0; u < 9; ++u) {
                U16 a;
                a.u = *(const uint4*)(xplane + aoffu[u] + xdo[sx]);
                #pragma unroll
                for (int g = 0; g < 4; ++g)
                    acc[u][g] = __builtin_amdgcn_mfma_f32_16x16x32_bf16(
                        a.s, bbuf[s & 1][g].s, acc[u][g], 0, 0, 0);
            }
        }

        __syncthreads();   // all waves done reading h planes before overwrite

        // ---- epilogue: gates; c in LDS; h -> LDS interior + global border ----
        // C output (u,r): pos (y,x) = (uy*4+q, ux*4+r), channel = sig*16+col
        float*  cb  = cL + sig * 2448 + q * 68 + col;
        ushort* eb  = hplanes + ple * 1568 + q * 112 + (col & 7);
        size_t  gqb = ((size_t)bb * HTOT + y0 + q) * WTOT + x0;
        ushort* hob = hout + ((size_t)sig * NPOS + gqb) * 16 + col;
        float*  ob  = out + gqb * 64 + sig * 16 + col;
        #pragma unroll
        for (int u = 0; u < 9; ++u) {
            const int uy = u / 3, ux = u % 3;
            #pragma unroll
            for (int r = 0; r < 4; ++r) {
                float zi = acc[u][0][r], zf = acc[u][1][r];
                float zg = acc[u][2][r], zo = acc[u][3][r];
                float co = cb[u * 272 + r * 17];
                float cn = hsig(zf) * co + hsig(zi) * ftanh(zg);
                cb[u * 272 + r * 17] = cn;
                float hn = hsig(zo) * ftanh(cn);
                ushort hb = f2bf(hn);
                eb[uy * 448 + ux * 32 + r * 8 + 120] = hb;   // LDS interior h(t)
                bool rowb = (uy == 0 && q == 0) || (uy == 2 && q == 3);
                bool colb = (ux == 0 && r == 0) || (ux == 2 && r == 3);
                if ((rowb || colb) && t < TT - 1)
                    hob[(uy * 384 + ux * 4 + r) * 16] = hb;  // border for neighbors
                if (t == TT - 1)
                    ob[(size_t)(uy * 384 + ux * 4 + r) * 64] = hn;
            }
        }

        __threadfence();   // h border stores device-visible
        __syncthreads();
        if (tid == 0 && t < TT - 1)
            __hip_atomic_fetch_add(cnt, 1u, __ATOMIC_RELEASE,
                                   __HIP_MEMORY_SCOPE_AGENT);
    }
}

extern "C" void kernel_launch(void* const* d_in, const int* in_sizes, int n_in,
                              void* d_out, int out_size, void* d_ws, size_t ws_size,
                              hipStream_t stream) {
    const float* x  = (const float*)d_in[0];
    const float* Wx = (const float*)d_in[1];
    const float* Wh = (const float*)d_in[2];
    const float* b  = (const float*)d_in[3];

    const size_t NX = (size_t)BB * TT * HTOT * WTOT * CINX;  // 9,437,184
    const size_t NH = (size_t)NPOS * FF;                     // 4,718,592

    char* ws = (char*)d_ws;
    ushort* xbf = (ushort*)ws;                  ws += NX * 2;              // 18.9 MB
    ushort* hS0 = (ushort*)ws;                  ws += NH * 2;              //  9.4 MB
    ushort* hS1 = (ushort*)ws;                  ws += NH * 2;              //  9.4 MB
    ushort* Bp  = (ushort*)ws;                  ws += (size_t)4*21*256*16; // 344 KB
    uint4*  zpad = (uint4*)ws;                  ws += 64;                  // 64 B zeros
    unsigned* cnt = (unsigned*)ws;                                         // 64 B

    hipMemsetAsync(hS0, 0, NH * 2, stream);
    hipMemsetAsync(hS1, 0, NH * 2, stream);
    hipMemsetAsync(zpad, 0, 64, stream);
    hipMemsetAsync(cnt, 0, 64, stream);

    conv_x_bf16<<<(int)((NX / 4 + 255) / 256), 256, 0, stream>>>(x, xbf, (int)(NX / 4));
    prep_w<<<(4 * 21 * 256 + 255) / 256, 256, 0, stream>>>(Wx, Wh, Bp);

    convlstm_fused<<<dim3(8, 8, 8), 256, 0, stream>>>(xbf, hS0, hS1, Bp, b, zpad,
                                                      cnt, (float*)d_out);
}

// Round 7
// 2010.736 us; speedup vs baseline: 1.3190x; 1.3190x over previous
//
#include <hip/hip_runtime.h>
#include <cmath>

// ConvLSTM2D forward, bf16 MFMA implicit GEMM, R12: persistent fused kernel,
// fixed barrier protocol (relaxed spin + ONE acquire fence/step), c in regs.
// B=8, T=16, H=W=96, Cin=8, F=64 (4F=256 gates), 3x3 SAME.
// R11 post-mortem: per-iteration ACQUIRE spin invalidated L1/L2 continuously
// -> 1.74GB cache-miss FETCH, MfmaUtil 7%, 2291us. Structure was correct.
// R12 deltas: (1) spin uses RELAXED loads; single fence(ACQUIRE,agent) after
// exit (stale-h correctness preserved, caches stay warm during spin);
// (2) release = syncthreads (drains all waves' stores) + tid0 fence(RELEASE,
// agent) + relaxed add; (3) c-state in registers cr[9][4] (cL LDS deleted:
// -39KB LDS, -bank conflicts, zero c memory traffic); (4) x async16 + B slab
// prefetch issued BEFORE the fence (read-only = stale-safe, latency hidden).
// Geometry unchanged: 512 blocks (8x8x8) = one exact residency round at
// 2 blocks/CU; block = 12x12 tile x 4 slices (wave=slice), 9 4x4 M-units.

#define HTOT 96
#define WTOT 96
#define CINX 8
#define FF   64
#define G4   256
#define BB   8
#define TT   16
#define NPOS (BB*HTOT*WTOT)        // 73728 global positions
#define NBLK 512

typedef __attribute__((ext_vector_type(8))) short short8;   // 8 bf16 = 4 VGPRs
typedef __attribute__((ext_vector_type(4))) float floatx4;

union U16 { uint4 u; short8 s; };

__device__ __forceinline__ float hsig(float z) {
    return fminf(fmaxf(0.2f * z + 0.5f, 0.f), 1.f);
}

__device__ __forceinline__ float ftanh(float x) {
    float e = __expf(-2.f * fabsf(x));
    float t = (1.f - e) / (1.f + e);
    return copysignf(t, x);
}

__device__ __forceinline__ ushort f2bf(float f) {            // RNE fp32->bf16
    unsigned u = __float_as_uint(f);
    u = (u + 0x7fff + ((u >> 16) & 1)) >> 16;
    return (ushort)u;
}

// async 16B global->LDS; LDS dest = uniform base + lane*16 (linear in tid)
__device__ __forceinline__ void async16(const void* g, void* l) {
    __builtin_amdgcn_global_load_lds(
        (const __attribute__((address_space(1))) void*)g,
        (__attribute__((address_space(3))) void*)l, 16, 0, 0);
}

// ---- prep: x fp32 -> bf16 (all T at once), layout [b,t,y,x,8] ----
__global__ __launch_bounds__(256) void conv_x_bf16(const float* __restrict__ x,
                                                   ushort* __restrict__ xbf, int n4) {
    int i = blockIdx.x * 256 + threadIdx.x;
    if (i >= n4) return;
    float4 v = ((const float4*)x)[i];
    ushort4 o;
    o.x = f2bf(v.x); o.y = f2bf(v.y); o.z = f2bf(v.z); o.w = f2bf(v.w);
    ((ushort4*)xbf)[i] = o;
}

// ---- prep: weights -> per-slice slab stream, slab s order = dx*6 + kh*3 + dy ----
// Bp[(slice*21+s)*256 + g*64 + lane] (16B units); lane(q,col) holds B rows q*8..q*8+7
__global__ __launch_bounds__(256) void prep_w(const float* __restrict__ Wx,
                                              const float* __restrict__ Wh,
                                              ushort* __restrict__ Bp) {
    int idx = blockIdx.x * 256 + threadIdx.x;
    if (idx >= 4 * 21 * 256) return;                 // 21504
    int lane = idx & 63;
    int g = (idx >> 6) & 3;
    int rest = idx >> 8;                             // slice*21 + s
    int s = rest % 21, slice = rest / 21;
    int q = lane >> 4, col = lane & 15;
    int n = g * 64 + slice * 16 + col;
    ushort o[8];
    if (s < 18) {
        int dxw = s / 6, rem = s - 6 * dxw;
        int khw = rem / 3, dyw = rem - 3 * khw;
        int tap = dyw * 3 + dxw;
        int cbase = khw * 32 + q * 8;
        #pragma unroll
        for (int j = 0; j < 8; ++j)
            o[j] = f2bf(Wh[((size_t)tap * FF + cbase + j) * G4 + n]);
    } else {
        int tap = (s - 18) * 4 + q;                  // packed x-taps; >8 -> zero pad
        #pragma unroll
        for (int j = 0; j < 8; ++j)
            o[j] = (tap < 9) ? f2bf(Wx[((size_t)tap * CINX + j) * G4 + n]) : (ushort)0;
    }
    U16 u;
    #pragma unroll
    for (int j = 0; j < 8; ++j) ((ushort*)&u)[j] = o[j];
    ((uint4*)Bp)[idx] = u.u;
}

// ---- fused 16-step kernel ----
__global__ __launch_bounds__(256, 2) void convlstm_fused(
    const ushort* __restrict__ xbf,
    ushort* __restrict__ hG0,             // h parity buffers [slice][pos][16] bf16
    ushort* __restrict__ hG1,
    const ushort* __restrict__ Bp,
    const float* __restrict__ bias,
    const uint4* __restrict__ zpad,       // 64B zeros for OOB x staging
    unsigned* __restrict__ cnt,           // grid barrier counter (zeroed)
    float* __restrict__ out)
{
    // h halo planes: plane pl = kh*4+q holds 8 ch (kh*32+q*8..) for 14x14 pos
    __shared__ __align__(16) ushort hplanes[8 * 1568];   // 25088 B
    __shared__ __align__(16) ushort xplane[1568];        //  3136 B (14x14 x 8ch)

    const int tid = threadIdx.x;
    const int x0 = blockIdx.x * 12, y0 = blockIdx.y * 12, bb = blockIdx.z;
    const int w = tid >> 6, lane = tid & 63, q = lane >> 4, col = lane & 15;
    const int sig = w;                                   // wave = slice

    const uint4* gBu = (const uint4*)Bp + (size_t)(sig * 21) * 256 + lane;

    // per-lane A offsets: M-unit u = (uy,ux) covers 4x4 pos; A-row m = col:
    // pos (y,x) = (uy*4 + (col>>2), ux*4 + (col&3)); halo idx = (y+dy)*14+(x+dx)
    int aoffu[9];
    #pragma unroll
    for (int u = 0; u < 9; ++u) {
        int uy = u / 3, ux = u % 3;
        int yu = uy * 4 + (col >> 2), xu = ux * 4 + (col & 3);
        aoffu[u] = (yu * 14 + xu) * 8;                   // ushort offset
    }
    int xdo[3];
    #pragma unroll
    for (int sx = 0; sx < 3; ++sx) {
        int tap = sx * 4 + q; if (tap > 8) tap = 8;      // padded taps: B rows 0
        xdo[sx] = ((tap / 3) * 14 + (tap % 3)) * 8;
    }
    float bv[4];
    #pragma unroll
    for (int g = 0; g < 4; ++g) bv[g] = bias[g * 64 + sig * 16 + col];

    const int ple = (sig >> 1) * 4 + (sig & 1) * 2 + (col >> 3);  // epilogue plane

    // zero-init LDS h planes (h(-1) = 0; ring OOB entries stay 0 forever)
    uint4 z4 = make_uint4(0, 0, 0, 0);
    for (int i = tid; i < 1568; i += 256) ((uint4*)hplanes)[i] = z4;

    // c-state lives in registers for all 16 steps (statically indexed)
    float cr[9][4];
    #pragma unroll
    for (int u = 0; u < 9; ++u)
        #pragma unroll
        for (int r = 0; r < 4; ++r) cr[u][r] = 0.f;

    for (int t = 0; t < TT; ++t) {
        const ushort* hin = (t & 1) ? hG0 : hG1;         // h(t-1)
        ushort* hout      = (t & 1) ? hG1 : hG0;         // h(t)

        // ---- prefetch read-only data BEFORE the fence (stale-safe) ----
        // x(t) 14x14 halo (async, lane-linear dest); xplane free after prev sync
        if (tid < 196) {
            int py = tid / 14, px = tid % 14;
            int gy = y0 - 1 + py, gx = x0 - 1 + px;
            bool ok = ((unsigned)gy < (unsigned)HTOT && (unsigned)gx < (unsigned)WTOT);
            const void* src = ok
                ? (const void*)(xbf + ((((size_t)bb * TT + t) * HTOT + gy) * WTOT + gx) * CINX)
                : (const void*)zpad;
            async16(src, xplane + tid * 8);
        }
        U16 bbuf[2][4];
        #pragma unroll
        for (int g = 0; g < 4; ++g) bbuf[0][g].u = gBu[g * 64];

        floatx4 acc[9][4];
        #pragma unroll
        for (int g = 0; g < 4; ++g) {
            float b0 = bv[g];
            #pragma unroll
            for (int u = 0; u < 9; ++u) acc[u][g] = (floatx4){b0, b0, b0, b0};
        }

        // ---- grid barrier: relaxed spin, ONE acquire fence after exit ----
        if (t) {
            if (tid == 0) {
                unsigned target = (unsigned)(NBLK * t);
                while (__hip_atomic_load(cnt, __ATOMIC_RELAXED,
                                         __HIP_MEMORY_SCOPE_AGENT) < target)
                    __builtin_amdgcn_s_sleep(2);
                __builtin_amdgcn_fence(__ATOMIC_ACQUIRE, "agent");  // L1/L2 inv once
            }
            __syncthreads();   // all threads ordered after the inv
        }

        // ---- stage 52-pos halo ring of h(t-1) from neighbors (post-fence) ----
        for (int e = tid; e < 416; e += 256) {
            int r = e >> 3, pl = e & 7;
            int py, px;
            if (r < 14)      { py = 0;  px = r; }
            else if (r < 28) { py = 13; px = r - 14; }
            else { int e2 = r - 28; py = 1 + (e2 >> 1); px = (e2 & 1) ? 13 : 0; }
            int gy = y0 - 1 + py, gx = x0 - 1 + px;
            if ((unsigned)gy < (unsigned)HTOT && (unsigned)gx < (unsigned)WTOT) {
                int sl = (pl >> 2) * 2 + ((pl & 3) >> 1), hf = pl & 1;
                size_t gpos = ((size_t)bb * HTOT + gy) * WTOT + gx;
                uint4 v = *(const uint4*)(hin + ((size_t)sl * NPOS + gpos) * 16 + hf * 8);
                *(uint4*)(hplanes + pl * 1568 + (py * 14 + px) * 8) = v;
            } // OOB ring entries stay zero from init (never written)
        }

        __syncthreads();   // ring ds_writes + x async16 drained; planes ready

        // ---- K-loop: 18 h-steps (dx,kh,dy) + 3 x-steps; B dbuf in regs ----
        const ushort* hAq = hplanes + q * 1568;
        #pragma unroll
        for (int dx = 0; dx < 3; ++dx)
        #pragma unroll
        for (int kh = 0; kh < 2; ++kh)
        #pragma unroll
        for (int dy = 0; dy < 3; ++dy) {
            const int s = dx * 6 + kh * 3 + dy;
            if (s < 20) {
                #pragma unroll
                for (int g = 0; g < 4; ++g)
                    bbuf[(s + 1) & 1][g].u = gBu[(s + 1) * 256 + g * 64];
            }
            #pragma unroll
            for (int u = 0; u < 9; ++u) {
                U16 a;
                a.u = *(const uint4*)(hAq + kh * 6272 + aoffu[u] + (dy * 14 + dx) * 8);
                #pragma unroll
                for (int g = 0; g < 4; ++g)
                    acc[u][g] = __builtin_amdgcn_mfma_f32_16x16x32_bf16(
                        a.s, bbuf[s & 1][g].s, acc[u][g], 0, 0, 0);
            }
        }
        #pragma unroll
        for (int sx = 0; sx < 3; ++sx) {
            const int s = 18 + sx;
            if (s < 20) {
                #pragma unroll
                for (int g = 0; g < 4; ++g)
                    bbuf[(s + 1) & 1][g].u = gBu[(s + 1) * 256 + g * 64];
            }
            #pragma unroll
            for (int u = 0; u < 9; ++u) {
                U16 a;
                a.u = *(const uint4*)(xplane + aoffu[u] + xdo[sx]);
                #pragma unroll
                for (int g = 0; g < 4; ++g)
                    acc[u][g] = __builtin_amdgcn_mfma_f32_16x16x32_bf16(
                        a.s, bbuf[s & 1][g].s, acc[u][g], 0, 0, 0);
            }
        }

        __syncthreads();   // all waves done reading h planes before overwrite

        // ---- epilogue: gates; c in regs; h -> LDS interior + global border ----
        // output (u,r): pos (y,x) = (uy*4+q, ux*4+r), channel = sig*16+col
        ushort* eb  = hplanes + ple * 1568 + q * 112 + (col & 7);
        size_t  gqb = ((size_t)bb * HTOT + y0 + q) * WTOT + x0;
        ushort* hob = hout + ((size_t)sig * NPOS + gqb) * 16 + col;
        float*  ob  = out + gqb * 64 + sig * 16 + col;
        #pragma unroll
        for (int u = 0; u < 9; ++u) {
            const int uy = u / 3, ux = u % 3;
            #pragma unroll
            for (int r = 0; r < 4; ++r) {
                float zi = acc[u][0][r], zf = acc[u][1][r];
                float zg = acc[u][2][r], zo = acc[u][3][r];
                float cn = hsig(zf) * cr[u][r] + hsig(zi) * ftanh(zg);
                cr[u][r] = cn;
                float hn = hsig(zo) * ftanh(cn);
                ushort hb = f2bf(hn);
                eb[uy * 448 + ux * 32 + r * 8 + 120] = hb;   // LDS interior h(t)
                bool rowb = (uy == 0 && q == 0) || (uy == 2 && q == 3);
                bool colb = (ux == 0 && r == 0) || (ux == 2 && r == 3);
                if ((rowb || colb) && t < TT - 1)
                    hob[(uy * 384 + ux * 4 + r) * 16] = hb;  // border for neighbors
                if (t == TT - 1)
                    ob[(size_t)(uy * 384 + ux * 4 + r) * 64] = hn;
            }
        }

        __syncthreads();   // drains every wave's border stores (vmcnt 0 at barrier)
        if (tid == 0 && t < TT - 1) {
            __builtin_amdgcn_fence(__ATOMIC_RELEASE, "agent");   // L2 writeback once
            __hip_atomic_fetch_add(cnt, 1u, __ATOMIC_RELAXED,
                                   __HIP_MEMORY_SCOPE_AGENT);
        }
    }
}

extern "C" void kernel_launch(void* const* d_in, const int* in_sizes, int n_in,
                              void* d_out, int out_size, void* d_ws, size_t ws_size,
                              hipStream_t stream) {
    const float* x  = (const float*)d_in[0];
    const float* Wx = (const float*)d_in[1];
    const float* Wh = (const float*)d_in[2];
    const float* b  = (const float*)d_in[3];

    const size_t NX = (size_t)BB * TT * HTOT * WTOT * CINX;  // 9,437,184
    const size_t NH = (size_t)NPOS * FF;                     // 4,718,592

    char* ws = (char*)d_ws;
    ushort* xbf = (ushort*)ws;                  ws += NX * 2;              // 18.9 MB
    ushort* hS0 = (ushort*)ws;                  ws += NH * 2;              //  9.4 MB
    ushort* hS1 = (ushort*)ws;                  ws += NH * 2;              //  9.4 MB
    ushort* Bp  = (ushort*)ws;                  ws += (size_t)4*21*256*16; // 344 KB
    uint4*  zpad = (uint4*)ws;                  ws += 64;                  // 64 B zeros
    unsigned* cnt = (unsigned*)ws;                                         // 64 B

    hipMemsetAsync(hS0, 0, NH * 2, stream);
    hipMemsetAsync(hS1, 0, NH * 2, stream);
    hipMemsetAsync(zpad, 0, 64, stream);
    hipMemsetAsync(cnt, 0, 64, stream);

    conv_x_bf16<<<(int)((NX / 4 + 255) / 256), 256, 0, stream>>>(x, xbf, (int)(NX / 4));
    prep_w<<<(4 * 21 * 256 + 255) / 256, 256, 0, stream>>>(Wx, Wh, Bp);

    convlstm_fused<<<dim3(8, 8, 8), 256, 0, stream>>>(xbf, hS0, hS1, Bp, b, zpad,
                                                      cnt, (float*)d_out);
}

// Round 8
// 1680.996 us; speedup vs baseline: 1.5777x; 1.1962x over previous
//
#include <hip/hip_runtime.h>
#include <cmath>

// ConvLSTM2D forward, bf16 MFMA implicit GEMM, R13: persistent fused kernel,
// FENCE-FREE step barrier: border-only coherent traffic, caches stay warm.
// B=8, T=16, H=W=96, Cin=8, F=64 (4F=256 gates), 3x3 SAME.
// R12 post-mortem: 8192 agent-scope fences (1 acquire+1 release per block-step)
// each invalidate/writeback a whole XCD L2 -> 2.7GB refetch fabric traffic at
// ~1.4TB/s = the entire 1.95ms runtime. Barrier protocol itself proven correct.
// R13 deltas:
//  (1) NO cache-wide fences at all.
//  (2) h border stores: inline-asm global_store_short sc0 sc1 (write-through
//      to coherence point); per-wave s_waitcnt vmcnt(0) before the end barrier
//      guarantees arrival before tid0's counter add.
//  (3) h ring loads: __hip_atomic_load RELAXED/AGENT u64 (coherence-point read;
//      same primitive as the R12 spin, which observably saw remote updates).
//  (4) B/x/bias loads untouched -> L1/L2 warm across all 16 steps.
// Geometry unchanged: 512 blocks (8x8x8), 2 blocks/CU by construction;
// block = 12x12 tile x 4 slices (wave=slice), 9 4x4 M-units; c in registers.

#define HTOT 96
#define WTOT 96
#define CINX 8
#define FF   64
#define G4   256
#define BB   8
#define TT   16
#define NPOS (BB*HTOT*WTOT)        // 73728 global positions
#define NBLK 512

typedef __attribute__((ext_vector_type(8))) short short8;   // 8 bf16 = 4 VGPRs
typedef __attribute__((ext_vector_type(4))) float floatx4;

union U16 { uint4 u; short8 s; };

__device__ __forceinline__ float hsig(float z) {
    return fminf(fmaxf(0.2f * z + 0.5f, 0.f), 1.f);
}

__device__ __forceinline__ float ftanh(float x) {
    float e = __expf(-2.f * fabsf(x));
    float t = (1.f - e) / (1.f + e);
    return copysignf(t, x);
}

__device__ __forceinline__ ushort f2bf(float f) {            // RNE fp32->bf16
    unsigned u = __float_as_uint(f);
    u = (u + 0x7fff + ((u >> 16) & 1)) >> 16;
    return (ushort)u;
}

// async 16B global->LDS; LDS dest = uniform base + lane*16 (linear in tid)
__device__ __forceinline__ void async16(const void* g, void* l) {
    __builtin_amdgcn_global_load_lds(
        (const __attribute__((address_space(1))) void*)g,
        (__attribute__((address_space(3))) void*)l, 16, 0, 0);
}

// coherence-point 8B load (bypasses stale L1/L2; relaxed agent atomic)
__device__ __forceinline__ unsigned long long coh_load8(const void* p) {
    return __hip_atomic_load((const unsigned long long*)p,
                             __ATOMIC_RELAXED, __HIP_MEMORY_SCOPE_AGENT);
}

// coherence-point 2B store (write-through past L2; sc0 sc1)
__device__ __forceinline__ void coh_store2(ushort* p, ushort v) {
    unsigned hv = v;
    asm volatile("global_store_short %0, %1, off sc0 sc1"
                 :: "v"(p), "v"(hv) : "memory");
}

// ---- prep: x fp32 -> bf16 (all T at once), layout [b,t,y,x,8] ----
__global__ __launch_bounds__(256) void conv_x_bf16(const float* __restrict__ x,
                                                   ushort* __restrict__ xbf, int n4) {
    int i = blockIdx.x * 256 + threadIdx.x;
    if (i >= n4) return;
    float4 v = ((const float4*)x)[i];
    ushort4 o;
    o.x = f2bf(v.x); o.y = f2bf(v.y); o.z = f2bf(v.z); o.w = f2bf(v.w);
    ((ushort4*)xbf)[i] = o;
}

// ---- prep: weights -> per-slice slab stream, slab s order = dx*6 + kh*3 + dy ----
// Bp[(slice*21+s)*256 + g*64 + lane] (16B units); lane(q,col) holds B rows q*8..q*8+7
__global__ __launch_bounds__(256) void prep_w(const float* __restrict__ Wx,
                                              const float* __restrict__ Wh,
                                              ushort* __restrict__ Bp) {
    int idx = blockIdx.x * 256 + threadIdx.x;
    if (idx >= 4 * 21 * 256) return;                 // 21504
    int lane = idx & 63;
    int g = (idx >> 6) & 3;
    int rest = idx >> 8;                             // slice*21 + s
    int s = rest % 21, slice = rest / 21;
    int q = lane >> 4, col = lane & 15;
    int n = g * 64 + slice * 16 + col;
    ushort o[8];
    if (s < 18) {
        int dxw = s / 6, rem = s - 6 * dxw;
        int khw = rem / 3, dyw = rem - 3 * khw;
        int tap = dyw * 3 + dxw;
        int cbase = khw * 32 + q * 8;
        #pragma unroll
        for (int j = 0; j < 8; ++j)
            o[j] = f2bf(Wh[((size_t)tap * FF + cbase + j) * G4 + n]);
    } else {
        int tap = (s - 18) * 4 + q;                  // packed x-taps; >8 -> zero pad
        #pragma unroll
        for (int j = 0; j < 8; ++j)
            o[j] = (tap < 9) ? f2bf(Wx[((size_t)tap * CINX + j) * G4 + n]) : (ushort)0;
    }
    U16 u;
    #pragma unroll
    for (int j = 0; j < 8; ++j) ((ushort*)&u)[j] = o[j];
    ((uint4*)Bp)[idx] = u.u;
}

// ---- fused 16-step kernel ----
__global__ __launch_bounds__(256, 2) void convlstm_fused(
    const ushort* __restrict__ xbf,
    ushort* __restrict__ hG0,             // h parity buffers [slice][pos][16] bf16
    ushort* __restrict__ hG1,
    const ushort* __restrict__ Bp,
    const float* __restrict__ bias,
    const uint4* __restrict__ zpad,       // 64B zeros for OOB x staging
    unsigned* __restrict__ cnt,           // grid barrier counter (zeroed)
    float* __restrict__ out)
{
    // h halo planes: plane pl = kh*4+q holds 8 ch (kh*32+q*8..) for 14x14 pos
    __shared__ __align__(16) ushort hplanes[8 * 1568];   // 25088 B
    __shared__ __align__(16) ushort xplane[1568];        //  3136 B (14x14 x 8ch)

    const int tid = threadIdx.x;
    const int x0 = blockIdx.x * 12, y0 = blockIdx.y * 12, bb = blockIdx.z;
    const int w = tid >> 6, lane = tid & 63, q = lane >> 4, col = lane & 15;
    const int sig = w;                                   // wave = slice

    const uint4* gBu = (const uint4*)Bp + (size_t)(sig * 21) * 256 + lane;

    // per-lane A offsets: M-unit u = (uy,ux) covers 4x4 pos; A-row m = col:
    // pos (y,x) = (uy*4 + (col>>2), ux*4 + (col&3)); halo idx = (y+dy)*14+(x+dx)
    int aoffu[9];
    #pragma unroll
    for (int u = 0; u < 9; ++u) {
        int uy = u / 3, ux = u % 3;
        int yu = uy * 4 + (col >> 2), xu = ux * 4 + (col & 3);
        aoffu[u] = (yu * 14 + xu) * 8;                   // ushort offset
    }
    int xdo[3];
    #pragma unroll
    for (int sx = 0; sx < 3; ++sx) {
        int tap = sx * 4 + q; if (tap > 8) tap = 8;      // padded taps: B rows 0
        xdo[sx] = ((tap / 3) * 14 + (tap % 3)) * 8;
    }
    float bv[4];
    #pragma unroll
    for (int g = 0; g < 4; ++g) bv[g] = bias[g * 64 + sig * 16 + col];

    const int ple = (sig >> 1) * 4 + (sig & 1) * 2 + (col >> 3);  // epilogue plane

    // zero-init LDS h planes (h(-1) = 0; ring OOB entries stay 0 forever)
    uint4 z4 = make_uint4(0, 0, 0, 0);
    for (int i = tid; i < 1568; i += 256) ((uint4*)hplanes)[i] = z4;

    // c-state lives in registers for all 16 steps (statically indexed)
    float cr[9][4];
    #pragma unroll
    for (int u = 0; u < 9; ++u)
        #pragma unroll
        for (int r = 0; r < 4; ++r) cr[u][r] = 0.f;

    for (int t = 0; t < TT; ++t) {
        const ushort* hin = (t & 1) ? hG0 : hG1;         // h(t-1)
        ushort* hout      = (t & 1) ? hG1 : hG0;         // h(t)

        // ---- prefetch read-only data BEFORE the spin (stale-safe, warm L2) ----
        if (tid < 196) {
            int py = tid / 14, px = tid % 14;
            int gy = y0 - 1 + py, gx = x0 - 1 + px;
            bool ok = ((unsigned)gy < (unsigned)HTOT && (unsigned)gx < (unsigned)WTOT);
            const void* src = ok
                ? (const void*)(xbf + ((((size_t)bb * TT + t) * HTOT + gy) * WTOT + gx) * CINX)
                : (const void*)zpad;
            async16(src, xplane + tid * 8);
        }
        U16 bbuf[2][4];
        #pragma unroll
        for (int g = 0; g < 4; ++g) bbuf[0][g].u = gBu[g * 64];

        floatx4 acc[9][4];
        #pragma unroll
        for (int g = 0; g < 4; ++g) {
            float b0 = bv[g];
            #pragma unroll
            for (int u = 0; u < 9; ++u) acc[u][g] = (floatx4){b0, b0, b0, b0};
        }

        // ---- grid barrier: relaxed spin; NO cache fences ----
        if (t) {
            if (tid == 0) {
                unsigned target = (unsigned)(NBLK * t);
                while (__hip_atomic_load(cnt, __ATOMIC_RELAXED,
                                         __HIP_MEMORY_SCOPE_AGENT) < target)
                    __builtin_amdgcn_s_sleep(2);
            }
            __syncthreads();
        }

        // ---- stage 52-pos halo ring of h(t-1): coherence-point u64 loads ----
        for (int e = tid; e < 416; e += 256) {
            int r = e >> 3, pl = e & 7;
            int py, px;
            if (r < 14)      { py = 0;  px = r; }
            else if (r < 28) { py = 13; px = r - 14; }
            else { int e2 = r - 28; py = 1 + (e2 >> 1); px = (e2 & 1) ? 13 : 0; }
            int gy = y0 - 1 + py, gx = x0 - 1 + px;
            if ((unsigned)gy < (unsigned)HTOT && (unsigned)gx < (unsigned)WTOT) {
                int sl = (pl >> 2) * 2 + ((pl & 3) >> 1), hf = pl & 1;
                size_t gpos = ((size_t)bb * HTOT + gy) * WTOT + gx;
                const ushort* sp = hin + ((size_t)sl * NPOS + gpos) * 16 + hf * 8;
                unsigned long long v0 = coh_load8(sp);
                unsigned long long v1 = coh_load8(sp + 4);
                ushort* dp = hplanes + pl * 1568 + (py * 14 + px) * 8;
                *(unsigned long long*)dp = v0;
                *(unsigned long long*)(dp + 4) = v1;
            } // OOB ring entries stay zero from init (never written)
        }

        __syncthreads();   // ring ds_writes + x async16 drained; planes ready

        // ---- K-loop: 18 h-steps (dx,kh,dy) + 3 x-steps; B dbuf in regs ----
        const ushort* hAq = hplanes + q * 1568;
        #pragma unroll
        for (int dx = 0; dx < 3; ++dx)
        #pragma unroll
        for (int kh = 0; kh < 2; ++kh)
        #pragma unroll
        for (int dy = 0; dy < 3; ++dy) {
            const int s = dx * 6 + kh * 3 + dy;
            if (s < 20) {
                #pragma unroll
                for (int g = 0; g < 4; ++g)
                    bbuf[(s + 1) & 1][g].u = gBu[(s + 1) * 256 + g * 64];
            }
            #pragma unroll
            for (int u = 0; u < 9; ++u) {
                U16 a;
                a.u = *(const uint4*)(hAq + kh * 6272 + aoffu[u] + (dy * 14 + dx) * 8);
                #pragma unroll
                for (int g = 0; g < 4; ++g)
                    acc[u][g] = __builtin_amdgcn_mfma_f32_16x16x32_bf16(
                        a.s, bbuf[s & 1][g].s, acc[u][g], 0, 0, 0);
            }
        }
        #pragma unroll
        for (int sx = 0; sx < 3; ++sx) {
            const int s = 18 + sx;
            if (s < 20) {
                #pragma unroll
                for (int g = 0; g < 4; ++g)
                    bbuf[(s + 1) & 1][g].u = gBu[(s + 1) * 256 + g * 64];
            }
            #pragma unroll
            for (int u = 0; u < 9; ++u) {
                U16 a;
                a.u = *(const uint4*)(xplane + aoffu[u] + xdo[sx]);
                #pragma unroll
                for (int g = 0; g < 4; ++g)
                    acc[u][g] = __builtin_amdgcn_mfma_f32_16x16x32_bf16(
                        a.s, bbuf[s & 1][g].s, acc[u][g], 0, 0, 0);
            }
        }

        __syncthreads();   // all waves done reading h planes before overwrite

        // ---- epilogue: gates; c in regs; h -> LDS interior + coherent border ----
        // output (u,r): pos (y,x) = (uy*4+q, ux*4+r), channel = sig*16+col
        ushort* eb  = hplanes + ple * 1568 + q * 112 + (col & 7);
        size_t  gqb = ((size_t)bb * HTOT + y0 + q) * WTOT + x0;
        ushort* hob = hout + ((size_t)sig * NPOS + gqb) * 16 + col;
        float*  ob  = out + gqb * 64 + sig * 16 + col;
        #pragma unroll
        for (int u = 0; u < 9; ++u) {
            const int uy = u / 3, ux = u % 3;
            #pragma unroll
            for (int r = 0; r < 4; ++r) {
                float zi = acc[u][0][r], zf = acc[u][1][r];
                float zg = acc[u][2][r], zo = acc[u][3][r];
                float cn = hsig(zf) * cr[u][r] + hsig(zi) * ftanh(zg);
                cr[u][r] = cn;
                float hn = hsig(zo) * ftanh(cn);
                ushort hb = f2bf(hn);
                eb[uy * 448 + ux * 32 + r * 8 + 120] = hb;   // LDS interior h(t)
                bool rowb = (uy == 0 && q == 0) || (uy == 2 && q == 3);
                bool colb = (ux == 0 && r == 0) || (ux == 2 && r == 3);
                if ((rowb || colb) && t < TT - 1)
                    coh_store2(hob + (uy * 384 + ux * 4 + r) * 16, hb);
                if (t == TT - 1)
                    ob[(size_t)(uy * 384 + ux * 4 + r) * 64] = hn;
            }
        }

        // per-wave: border stores reached the coherence point before barrier
        asm volatile("s_waitcnt vmcnt(0)" ::: "memory");
        __syncthreads();
        if (tid == 0 && t < TT - 1)
            __hip_atomic_fetch_add(cnt, 1u, __ATOMIC_RELAXED,
                                   __HIP_MEMORY_SCOPE_AGENT);
    }
}

extern "C" void kernel_launch(void* const* d_in, const int* in_sizes, int n_in,
                              void* d_out, int out_size, void* d_ws, size_t ws_size,
                              hipStream_t stream) {
    const float* x  = (const float*)d_in[0];
    const float* Wx = (const float*)d_in[1];
    const float* Wh = (const float*)d_in[2];
    const float* b  = (const float*)d_in[3];

    const size_t NX = (size_t)BB * TT * HTOT * WTOT * CINX;  // 9,437,184
    const size_t NH = (size_t)NPOS * FF;                     // 4,718,592

    char* ws = (char*)d_ws;
    ushort* xbf = (ushort*)ws;                  ws += NX * 2;              // 18.9 MB
    ushort* hS0 = (ushort*)ws;                  ws += NH * 2;              //  9.4 MB
    ushort* hS1 = (ushort*)ws;                  ws += NH * 2;              //  9.4 MB
    ushort* Bp  = (ushort*)ws;                  ws += (size_t)4*21*256*16; // 344 KB
    uint4*  zpad = (uint4*)ws;                  ws += 64;                  // 64 B zeros
    unsigned* cnt = (unsigned*)ws;                                         // 64 B

    hipMemsetAsync(hS0, 0, NH * 2, stream);
    hipMemsetAsync(hS1, 0, NH * 2, stream);
    hipMemsetAsync(zpad, 0, 64, stream);
    hipMemsetAsync(cnt, 0, 64, stream);

    conv_x_bf16<<<(int)((NX / 4 + 255) / 256), 256, 0, stream>>>(x, xbf, (int)(NX / 4));
    prep_w<<<(4 * 21 * 256 + 255) / 256, 256, 0, stream>>>(Wx, Wh, Bp);

    convlstm_fused<<<dim3(8, 8, 8), 256, 0, stream>>>(xbf, hS0, hS1, Bp, b, zpad,
                                                      cnt, (float*)d_out);
}

// Round 9
// 1672.745 us; speedup vs baseline: 1.5855x; 1.0049x over previous
//
#include <hip/hip_runtime.h>
#include <cmath>

// ConvLSTM2D forward, bf16 MFMA implicit GEMM, R14: persistent fused kernel,
// COALESCED compact border exchange (the R11-R13 2GB FETCH was 2B-scatter
// write-through amplification + RMW, constant across all fence protocols).
// B=8, T=16, H=W=96, Cin=8, F=64 (4F=256 gates), 3x3 SAME.
// R14 deltas vs R13:
//  - border h exchanged via compact bord[tile][48 slot][64 ch] bf16 buffers
//    (parity double-buffered, 3MB each): stores are lane-contiguous 32B runs
//    (sc0 sc1 write-through), ~6KB/block-step vs 90KB+180KB RMW before.
//  - ring loads: 16B-aligned coh u64 pairs from neighbors' border slots.
//  - hG0/hG1 global h buffers + memsets deleted (interior h never leaves LDS).
//  - everything else unchanged (relaxed spin barrier, c in regs, B/x warm L2).
// Slot map: top row y=0 -> 0..11 (x), bottom y=11 -> 12..23, left x=0 ->
// 24..35 (y), right x=11 -> 36..47; corners stored twice, readers use either.

#define HTOT 96
#define WTOT 96
#define CINX 8
#define FF   64
#define G4   256
#define BB   8
#define TT   16
#define NPOS (BB*HTOT*WTOT)        // 73728 global positions
#define NBLK 512

typedef __attribute__((ext_vector_type(8))) short short8;   // 8 bf16 = 4 VGPRs
typedef __attribute__((ext_vector_type(4))) float floatx4;

union U16 { uint4 u; short8 s; };

__device__ __forceinline__ float hsig(float z) {
    return fminf(fmaxf(0.2f * z + 0.5f, 0.f), 1.f);
}

__device__ __forceinline__ float ftanh(float x) {
    float e = __expf(-2.f * fabsf(x));
    float t = (1.f - e) / (1.f + e);
    return copysignf(t, x);
}

__device__ __forceinline__ ushort f2bf(float f) {            // RNE fp32->bf16
    unsigned u = __float_as_uint(f);
    u = (u + 0x7fff + ((u >> 16) & 1)) >> 16;
    return (ushort)u;
}

// async 16B global->LDS; LDS dest = uniform base + lane*16 (linear in tid)
__device__ __forceinline__ void async16(const void* g, void* l) {
    __builtin_amdgcn_global_load_lds(
        (const __attribute__((address_space(1))) void*)g,
        (__attribute__((address_space(3))) void*)l, 16, 0, 0);
}

// coherence-point 8B load (bypasses stale L1/L2; relaxed agent atomic)
__device__ __forceinline__ unsigned long long coh_load8(const void* p) {
    return __hip_atomic_load((const unsigned long long*)p,
                             __ATOMIC_RELAXED, __HIP_MEMORY_SCOPE_AGENT);
}

// coherence-point 2B store (write-through past L2; sc0 sc1)
__device__ __forceinline__ void coh_store2(ushort* p, ushort v) {
    unsigned hv = v;
    asm volatile("global_store_short %0, %1, off sc0 sc1"
                 :: "v"(p), "v"(hv) : "memory");
}

// ---- prep: x fp32 -> bf16 (all T at once), layout [b,t,y,x,8] ----
__global__ __launch_bounds__(256) void conv_x_bf16(const float* __restrict__ x,
                                                   ushort* __restrict__ xbf, int n4) {
    int i = blockIdx.x * 256 + threadIdx.x;
    if (i >= n4) return;
    float4 v = ((const float4*)x)[i];
    ushort4 o;
    o.x = f2bf(v.x); o.y = f2bf(v.y); o.z = f2bf(v.z); o.w = f2bf(v.w);
    ((ushort4*)xbf)[i] = o;
}

// ---- prep: weights -> per-slice slab stream, slab s order = dx*6 + kh*3 + dy ----
// Bp[(slice*21+s)*256 + g*64 + lane] (16B units); lane(q,col) holds B rows q*8..q*8+7
__global__ __launch_bounds__(256) void prep_w(const float* __restrict__ Wx,
                                              const float* __restrict__ Wh,
                                              ushort* __restrict__ Bp) {
    int idx = blockIdx.x * 256 + threadIdx.x;
    if (idx >= 4 * 21 * 256) return;                 // 21504
    int lane = idx & 63;
    int g = (idx >> 6) & 3;
    int rest = idx >> 8;                             // slice*21 + s
    int s = rest % 21, slice = rest / 21;
    int q = lane >> 4, col = lane & 15;
    int n = g * 64 + slice * 16 + col;
    ushort o[8];
    if (s < 18) {
        int dxw = s / 6, rem = s - 6 * dxw;
        int khw = rem / 3, dyw = rem - 3 * khw;
        int tap = dyw * 3 + dxw;
        int cbase = khw * 32 + q * 8;
        #pragma unroll
        for (int j = 0; j < 8; ++j)
            o[j] = f2bf(Wh[((size_t)tap * FF + cbase + j) * G4 + n]);
    } else {
        int tap = (s - 18) * 4 + q;                  // packed x-taps; >8 -> zero pad
        #pragma unroll
        for (int j = 0; j < 8; ++j)
            o[j] = (tap < 9) ? f2bf(Wx[((size_t)tap * CINX + j) * G4 + n]) : (ushort)0;
    }
    U16 u;
    #pragma unroll
    for (int j = 0; j < 8; ++j) ((ushort*)&u)[j] = o[j];
    ((uint4*)Bp)[idx] = u.u;
}

// ---- fused 16-step kernel ----
__global__ __launch_bounds__(256, 2) void convlstm_fused(
    const ushort* __restrict__ xbf,
    ushort* __restrict__ bord0,           // [tile][48][64] bf16 border, parity 0
    ushort* __restrict__ bord1,           // parity 1
    const ushort* __restrict__ Bp,
    const float* __restrict__ bias,
    const uint4* __restrict__ zpad,       // 64B zeros for OOB x staging
    unsigned* __restrict__ cnt,           // grid barrier counter (zeroed)
    float* __restrict__ out)
{
    // h halo planes: plane pl = kh*4+q holds 8 ch (kh*32+q*8..) for 14x14 pos
    __shared__ __align__(16) ushort hplanes[8 * 1568];   // 25088 B
    __shared__ __align__(16) ushort xplane[1568];        //  3136 B (14x14 x 8ch)

    const int tid = threadIdx.x;
    const int bx = blockIdx.x, by = blockIdx.y, bb = blockIdx.z;
    const int x0 = bx * 12, y0 = by * 12;
    const int w = tid >> 6, lane = tid & 63, q = lane >> 4, col = lane & 15;
    const int sig = w;                                   // wave = slice
    const int tile = (bb * 8 + by) * 8 + bx;             // 512 tiles

    const uint4* gBu = (const uint4*)Bp + (size_t)(sig * 21) * 256 + lane;

    // per-lane A offsets: M-unit u = (uy,ux) covers 4x4 pos; A-row m = col:
    // pos (y,x) = (uy*4 + (col>>2), ux*4 + (col&3)); halo idx = (y+dy)*14+(x+dx)
    int aoffu[9];
    #pragma unroll
    for (int u = 0; u < 9; ++u) {
        int uy = u / 3, ux = u % 3;
        int yu = uy * 4 + (col >> 2), xu = ux * 4 + (col & 3);
        aoffu[u] = (yu * 14 + xu) * 8;                   // ushort offset
    }
    int xdo[3];
    #pragma unroll
    for (int sx = 0; sx < 3; ++sx) {
        int tap = sx * 4 + q; if (tap > 8) tap = 8;      // padded taps: B rows 0
        xdo[sx] = ((tap / 3) * 14 + (tap % 3)) * 8;
    }
    float bv[4];
    #pragma unroll
    for (int g = 0; g < 4; ++g) bv[g] = bias[g * 64 + sig * 16 + col];

    const int ple = (sig >> 1) * 4 + (sig & 1) * 2 + (col >> 3);  // epilogue plane

    // zero-init LDS h planes (h(-1) = 0; ring OOB entries stay 0 forever)
    uint4 z4 = make_uint4(0, 0, 0, 0);
    for (int i = tid; i < 1568; i += 256) ((uint4*)hplanes)[i] = z4;

    // c-state lives in registers for all 16 steps (statically indexed)
    float cr[9][4];
    #pragma unroll
    for (int u = 0; u < 9; ++u)
        #pragma unroll
        for (int r = 0; r < 4; ++r) cr[u][r] = 0.f;

    for (int t = 0; t < TT; ++t) {
        const ushort* bordR = (t & 1) ? bord0 : bord1;   // borders of h(t-1)
        ushort*       bordW = (t & 1) ? bord1 : bord0;   // borders of h(t)

        // ---- prefetch read-only data BEFORE the spin (stale-safe, warm L2) ----
        if (tid < 196) {
            int py = tid / 14, px = tid % 14;
            int gy = y0 - 1 + py, gx = x0 - 1 + px;
            bool ok = ((unsigned)gy < (unsigned)HTOT && (unsigned)gx < (unsigned)WTOT);
            const void* src = ok
                ? (const void*)(xbf + ((((size_t)bb * TT + t) * HTOT + gy) * WTOT + gx) * CINX)
                : (const void*)zpad;
            async16(src, xplane + tid * 8);
        }
        U16 bbuf[2][4];
        #pragma unroll
        for (int g = 0; g < 4; ++g) bbuf[0][g].u = gBu[g * 64];

        floatx4 acc[9][4];
        #pragma unroll
        for (int g = 0; g < 4; ++g) {
            float b0 = bv[g];
            #pragma unroll
            for (int u = 0; u < 9; ++u) acc[u][g] = (floatx4){b0, b0, b0, b0};
        }

        // ---- grid barrier: relaxed spin; no cache fences ----
        if (t) {
            if (tid == 0) {
                unsigned target = (unsigned)(NBLK * t);
                while (__hip_atomic_load(cnt, __ATOMIC_RELAXED,
                                         __HIP_MEMORY_SCOPE_AGENT) < target)
                    __builtin_amdgcn_s_sleep(2);
            }
            __syncthreads();
        }

        // ---- stage 52-pos halo ring of h(t-1) from neighbor border slots ----
        for (int e = tid; e < 416; e += 256) {
            int r = e >> 3, pl = e & 7;
            int py, px;
            if (r < 14)      { py = 0;  px = r; }
            else if (r < 28) { py = 13; px = r - 14; }
            else { int e2 = r - 28; py = 1 + (e2 >> 1); px = (e2 & 1) ? 13 : 0; }
            int nbx = bx, nby = by, slot;
            if (py == 0) {
                nby = by - 1;
                if (px == 0)       { nbx = bx - 1; slot = 23; }
                else if (px == 13) { nbx = bx + 1; slot = 12; }
                else               { slot = 12 + px - 1; }
            } else if (py == 13) {
                nby = by + 1;
                if (px == 0)       { nbx = bx - 1; slot = 11; }
                else if (px == 13) { nbx = bx + 1; slot = 0; }
                else               { slot = px - 1; }
            } else if (px == 0) { nbx = bx - 1; slot = 36 + py - 1; }
            else                { nbx = bx + 1; slot = 24 + py - 1; }
            if ((unsigned)nbx < 8u && (unsigned)nby < 8u) {
                int sl = (pl >> 2) * 2 + ((pl & 3) >> 1), hf = pl & 1;
                const ushort* sp = bordR
                    + ((size_t)((bb * 8 + nby) * 8 + nbx) * 48 + slot) * 64
                    + sl * 16 + hf * 8;
                unsigned long long v0 = coh_load8(sp);
                unsigned long long v1 = coh_load8(sp + 4);
                ushort* dp = hplanes + pl * 1568 + (py * 14 + px) * 8;
                *(unsigned long long*)dp = v0;
                *(unsigned long long*)(dp + 4) = v1;
            } // OOB ring entries stay zero from init (never written)
        }

        __syncthreads();   // ring ds_writes + x async16 drained; planes ready

        // ---- K-loop: 18 h-steps (dx,kh,dy) + 3 x-steps; B dbuf in regs ----
        const ushort* hAq = hplanes + q * 1568;
        #pragma unroll
        for (int dx = 0; dx < 3; ++dx)
        #pragma unroll
        for (int kh = 0; kh < 2; ++kh)
        #pragma unroll
        for (int dy = 0; dy < 3; ++dy) {
            const int s = dx * 6 + kh * 3 + dy;
            if (s < 20) {
                #pragma unroll
                for (int g = 0; g < 4; ++g)
                    bbuf[(s + 1) & 1][g].u = gBu[(s + 1) * 256 + g * 64];
            }
            #pragma unroll
            for (int u = 0; u < 9; ++u) {
                U16 a;
                a.u = *(const uint4*)(hAq + kh * 6272 + aoffu[u] + (dy * 14 + dx) * 8);
                #pragma unroll
                for (int g = 0; g < 4; ++g)
                    acc[u][g] = __builtin_amdgcn_mfma_f32_16x16x32_bf16(
                        a.s, bbuf[s & 1][g].s, acc[u][g], 0, 0, 0);
            }
        }
        #pragma unroll
        for (int sx = 0; sx < 3; ++sx) {
            const int s = 18 + sx;
            if (s < 20) {
                #pragma unroll
                for (int g = 0; g < 4; ++g)
                    bbuf[(s + 1) & 1][g].u = gBu[(s + 1) * 256 + g * 64];
            }
            #pragma unroll
            for (int u = 0; u < 9; ++u) {
                U16 a;
                a.u = *(const uint4*)(xplane + aoffu[u] + xdo[sx]);
                #pragma unroll
                for (int g = 0; g < 4; ++g)
                    acc[u][g] = __builtin_amdgcn_mfma_f32_16x16x32_bf16(
                        a.s, bbuf[s & 1][g].s, acc[u][g], 0, 0, 0);
            }
        }

        __syncthreads();   // all waves done reading h planes before overwrite

        // ---- epilogue: gates; c in regs; h -> LDS interior + compact border ----
        // output (u,r): pos (y,x) = (uy*4+q, ux*4+r), channel = sig*16+col
        ushort* eb = hplanes + ple * 1568 + q * 112 + (col & 7);
        ushort* bw = bordW + (size_t)tile * 48 * 64 + sig * 16 + col;
        size_t  gqb = ((size_t)bb * HTOT + y0 + q) * WTOT + x0;
        float*  ob  = out + gqb * 64 + sig * 16 + col;
        #pragma unroll
        for (int u = 0; u < 9; ++u) {
            const int uy = u / 3, ux = u % 3;
            #pragma unroll
            for (int r = 0; r < 4; ++r) {
                float zi = acc[u][0][r], zf = acc[u][1][r];
                float zg = acc[u][2][r], zo = acc[u][3][r];
                float cn = hsig(zf) * cr[u][r] + hsig(zi) * ftanh(zg);
                cr[u][r] = cn;
                float hn = hsig(zo) * ftanh(cn);
                ushort hb = f2bf(hn);
                eb[uy * 448 + ux * 32 + r * 8 + 120] = hb;   // LDS interior h(t)
                if (t < TT - 1) {
                    if (uy == 0 && q == 0)                   // top row slot x
                        coh_store2(bw + (ux * 4 + r) * 64, hb);
                    if (uy == 2 && q == 3)                   // bottom row
                        coh_store2(bw + (12 + ux * 4 + r) * 64, hb);
                    if (ux == 0 && r == 0)                   // left col slot y
                        coh_store2(bw + (24 + uy * 4 + q) * 64, hb);
                    if (ux == 2 && r == 3)                   // right col
                        coh_store2(bw + (36 + uy * 4 + q) * 64, hb);
                }
                if (t == TT - 1)
                    ob[(size_t)(uy * 384 + ux * 4 + r) * 64] = hn;
            }
        }

        // per-wave: border stores reached the coherence point before barrier
        asm volatile("s_waitcnt vmcnt(0)" ::: "memory");
        __syncthreads();
        if (tid == 0 && t < TT - 1)
            __hip_atomic_fetch_add(cnt, 1u, __ATOMIC_RELAXED,
                                   __HIP_MEMORY_SCOPE_AGENT);
    }
}

extern "C" void kernel_launch(void* const* d_in, const int* in_sizes, int n_in,
                              void* d_out, int out_size, void* d_ws, size_t ws_size,
                              hipStream_t stream) {
    const float* x  = (const float*)d_in[0];
    const float* Wx = (const float*)d_in[1];
    const float* Wh = (const float*)d_in[2];
    const float* b  = (const float*)d_in[3];

    const size_t NX = (size_t)BB * TT * HTOT * WTOT * CINX;  // 9,437,184
    const size_t NBORD = (size_t)NBLK * 48 * 64;             // 1,572,864 ushorts

    char* ws = (char*)d_ws;
    ushort* xbf   = (ushort*)ws;                ws += NX * 2;              // 18.9 MB
    ushort* bord0 = (ushort*)ws;                ws += NBORD * 2;           //  3.0 MB
    ushort* bord1 = (ushort*)ws;                ws += NBORD * 2;           //  3.0 MB
    ushort* Bp    = (ushort*)ws;                ws += (size_t)4*21*256*16; // 344 KB
    uint4*  zpad  = (uint4*)ws;                 ws += 64;                  // 64 B
    unsigned* cnt = (unsigned*)ws;                                         // 64 B

    hipMemsetAsync(bord0, 0, NBORD * 2, stream);
    hipMemsetAsync(bord1, 0, NBORD * 2, stream);
    hipMemsetAsync(zpad, 0, 64, stream);
    hipMemsetAsync(cnt, 0, 64, stream);

    conv_x_bf16<<<(int)((NX / 4 + 255) / 256), 256, 0, stream>>>(x, xbf, (int)(NX / 4));
    prep_w<<<(4 * 21 * 256 + 255) / 256, 256, 0, stream>>>(Wx, Wh, Bp);

    convlstm_fused<<<dim3(8, 8, 8), 256, 0, stream>>>(xbf, bord0, bord1, Bp, b, zpad,
                                                      cnt, (float*)d_out);
}